// Round 18
// baseline (318.787 us; speedup 1.0000x reference)
//
#include <hip/hip_runtime.h>
#include <cstdint>

// Problem constants (from reference)
constexpr int B_   = 4096;
constexpr int T_   = 512;
constexpr int DIN  = 10;
constexpr int H_   = 20;
constexpr int DOUT = 2;

typedef float    v2f  __attribute__((ext_vector_type(2)));
typedef _Float16 h2t  __attribute__((ext_vector_type(2)));
typedef __fp16   fp2t __attribute__((ext_vector_type(2)));

constexpr float SCL = 2.885390082f;   // 2*log2(e), folded into weights/biases

#define CFENCE() asm volatile("" ::: "memory")

// v_dot2_f32_f16: D = a.x*b.x + a.y*b.y + c (f32 accumulate, one instr)
__device__ __forceinline__ float fdot2(h2t a, h2t b, float c) {
#if __has_builtin(__builtin_amdgcn_fdot2)
    return __builtin_amdgcn_fdot2(a, b, c, false);
#else
    return fmaf((float)a.x, (float)b.x, fmaf((float)a.y, (float)b.y, c));
#endif
}

// tanh from PRE-SCALED input s = 2*log2e*v: 4-op chain, exact saturation
__device__ __forceinline__ float tanh_pre(float s) {
    float e = __builtin_amdgcn_exp2f(s);
    float r = __builtin_amdgcn_rcpf(e + 1.0f);
    return fmaf(-2.0f, r, 1.0f);
}

union HI { int i; h2t h; fp2t f; };

// quad_perm DPP ctrl imms (self-calibrated below, exact codes non-critical)
#define QP1 0x39   // [1,2,3,0]
#define QP2 0x4E   // [2,3,0,1]
#define QP3 0x93   // [3,0,1,2]

// 4 lanes per sample (quad = sample), 16 samples/wave, 256 blocks.
// Lane c (=lane&3) owns rows 5c..5c+4 of BOTH layers.
// Per step: pack 10 outputs -> 5 f16x2 dwords; all-gather via 15
// v_mov_dpp quad_perm (pure VALU -- ZERO DS ops on the recurrent chain,
// which R9-R16 showed cost ~38cyc each serially).
// Skewed recurrence (R13 semantics, verified): per step compute
// h1(tau) [L0] and h2(tau-1) [L1] from committed register state.
// amdgpu_waves_per_eu(1,1): pin occupancy so the allocator has no
// incentive to demote the ~240-VGPR working set (R7/R12/R17 failure mode).
extern "C" __global__ void __launch_bounds__(64)
__attribute__((amdgpu_waves_per_eu(1, 1)))
rnn_quad(const float* __restrict__ x,
         const float* __restrict__ w_ih0, const float* __restrict__ w_hh0,
         const float* __restrict__ b_ih0, const float* __restrict__ b_hh0,
         const float* __restrict__ w_ih1, const float* __restrict__ w_hh1,
         const float* __restrict__ b_ih1, const float* __restrict__ b_hh1,
         const float* __restrict__ fc_w, const float* __restrict__ fc_b,
         float* __restrict__ out)
{
    const int lane = threadIdx.x;
    const int q    = lane >> 2;          // quad = sample slot 0..15
    const int c    = lane & 3;           // chunk (rows 5c..5c+4)
    const int samp = blockIdx.x * 16 + q;   // grid=256 -> always < B_

    __shared__ float ldsF[16][20];       // epilogue FC buffer only

    // ---- probe the actual quad_perm source chunk for each gather slot ----
    int cid[4];
    cid[0] = c;
    cid[1] = __builtin_amdgcn_mov_dpp(c, QP1, 0xF, 0xF, true);
    cid[2] = __builtin_amdgcn_mov_dpp(c, QP2, 0xF, 0xF, true);
    cid[3] = __builtin_amdgcn_mov_dpp(c, QP3, 0xF, 0xF, true);

    // ---- weights (f16 pairs, pre-scaled), laid out in gather-slot order ----
    // State dword layout per chunk j: d0=(h1[5j],h1[5j+1]) d1=(h1[5j+2],h1[5j+3])
    //   d2=(h1[5j+4],h2[5j]) d3=(h2[5j+1],h2[5j+2]) d4=(h2[5j+3],h2[5j+4])
    h2t W0[5][12];   // L0: per row, slot g contributes 3 dwords (last half-wasted)
    h2t W1[5][20];   // L1: per row, slot g contributes 5 dwords (zero waste)
    h2t WX[5][5];    // x-projection (f16 pairs)
    float bx[5], b1v[5];
    #pragma unroll
    for (int r = 0; r < 5; ++r) {
        const int rho = 5 * c + r;
        #pragma unroll
        for (int g = 0; g < 4; ++g) {
            const int bse = 5 * cid[g];
            const float* u0 = w_hh0 + rho * H_ + bse;
            const float* ui = w_ih1 + rho * H_ + bse;
            const float* uh = w_hh1 + rho * H_ + bse;
            W0[r][g*3+0] = h2t{(_Float16)(SCL*u0[0]), (_Float16)(SCL*u0[1])};
            W0[r][g*3+1] = h2t{(_Float16)(SCL*u0[2]), (_Float16)(SCL*u0[3])};
            W0[r][g*3+2] = h2t{(_Float16)(SCL*u0[4]), (_Float16)0.f};
            W1[r][g*5+0] = h2t{(_Float16)(SCL*ui[0]), (_Float16)(SCL*ui[1])};
            W1[r][g*5+1] = h2t{(_Float16)(SCL*ui[2]), (_Float16)(SCL*ui[3])};
            W1[r][g*5+2] = h2t{(_Float16)(SCL*ui[4]), (_Float16)(SCL*uh[0])};
            W1[r][g*5+3] = h2t{(_Float16)(SCL*uh[1]), (_Float16)(SCL*uh[2])};
            W1[r][g*5+4] = h2t{(_Float16)(SCL*uh[3]), (_Float16)(SCL*uh[4])};
        }
        #pragma unroll
        for (int k = 0; k < 5; ++k)
            WX[r][k] = h2t{(_Float16)(SCL * w_ih0[rho * DIN + 2*k]),
                           (_Float16)(SCL * w_ih0[rho * DIN + 2*k + 1])};
        bx[r]  = SCL * (b_ih0[rho] + b_hh0[rho]);
        b1v[r] = SCL * (b_ih1[rho] + b_hh1[rho]);
    }

    // ---- state: S[g][k] = dword k of chunk cid[g]; zero-init ----
    h2t S[4][5];
    #pragma unroll
    for (int g = 0; g < 4; ++g)
        #pragma unroll
        for (int k = 0; k < 5; ++k) S[g][k] = h2t{(_Float16)0.f, (_Float16)0.f};

    const float* xr = x + (size_t)samp * (T_ * DIN);

    // x pipeline: raw v2f row -> f16 dwords -> xp[5]
    v2f xraw[5];
    float xp[5];
    auto load_raw = [&](int t) {
        const v2f* p = reinterpret_cast<const v2f*>(xr + (size_t)t * DIN);
        #pragma unroll
        for (int k = 0; k < 5; ++k) xraw[k] = p[k];
    };
    auto make_xp = [&]() {
        HI xd[5];
        #pragma unroll
        for (int k = 0; k < 5; ++k)
            xd[k].f = __builtin_amdgcn_cvt_pkrtz(xraw[k].x, xraw[k].y);
        #pragma unroll
        for (int r = 0; r < 5; ++r) {
            float p0 = bx[r], p1 = 0.f;
            p0 = fdot2(xd[0].h, WX[r][0], p0);
            p1 = fdot2(xd[1].h, WX[r][1], p1);
            p0 = fdot2(xd[2].h, WX[r][2], p0);
            p1 = fdot2(xd[3].h, WX[r][3], p1);
            p0 = fdot2(xd[4].h, WX[r][4], p0);
            xp[r] = p0 + p1;
        }
    };

    // one skewed step (KEEP=0 only at tau=0 kills the undefined L1 output)
    auto full_step = [&](float keep) {
        float h1n[5], h2n[5];
        #pragma unroll
        for (int r = 0; r < 5; ++r) {
            // ---- L0: 12 dot2, 2 chains ----
            float a0 = xp[r], a1 = 0.f;
            #pragma unroll
            for (int g = 0; g < 4; ++g) {
                a0 = fdot2(S[g][0], W0[r][g*3+0], a0);
                a1 = fdot2(S[g][1], W0[r][g*3+1], a1);
                a0 = fdot2(S[g][2], W0[r][g*3+2], a0);
            }
            h1n[r] = tanh_pre(a0 + a1);
            // ---- L1: 20 dot2, 4 chains (old state: skewed) ----
            float q0 = b1v[r], q1 = 0.f, q2 = 0.f, q3 = 0.f;
            #pragma unroll
            for (int g = 0; g < 4; ++g) {
                q0 = fdot2(S[g][0], W1[r][g*5+0], q0);
                q1 = fdot2(S[g][1], W1[r][g*5+1], q1);
                q2 = fdot2(S[g][2], W1[r][g*5+2], q2);
                q3 = fdot2(S[g][3], W1[r][g*5+3], q3);
                q0 = fdot2(S[g][4], W1[r][g*5+4], q0);
            }
            h2n[r] = keep * tanh_pre((q0 + q1) + (q2 + q3));
        }
        // ---- pack 10 outputs into 5 dwords ----
        HI d0, d1, d2, d3, d4;
        d0.f = __builtin_amdgcn_cvt_pkrtz(h1n[0], h1n[1]);
        d1.f = __builtin_amdgcn_cvt_pkrtz(h1n[2], h1n[3]);
        d2.f = __builtin_amdgcn_cvt_pkrtz(h1n[4], h2n[0]);
        d3.f = __builtin_amdgcn_cvt_pkrtz(h2n[1], h2n[2]);
        d4.f = __builtin_amdgcn_cvt_pkrtz(h2n[3], h2n[4]);
        // ---- commit own chunk + quad all-gather (15 VALU dpp, zero DS) ----
        S[0][0] = d0.h; S[0][1] = d1.h; S[0][2] = d2.h; S[0][3] = d3.h; S[0][4] = d4.h;
#define GSLOT(G, CTRL)                                                          \
        { HI t0_, t1_, t2_, t3_, t4_;                                           \
          t0_.i = __builtin_amdgcn_mov_dpp(d0.i, CTRL, 0xF, 0xF, true);         \
          t1_.i = __builtin_amdgcn_mov_dpp(d1.i, CTRL, 0xF, 0xF, true);         \
          t2_.i = __builtin_amdgcn_mov_dpp(d2.i, CTRL, 0xF, 0xF, true);         \
          t3_.i = __builtin_amdgcn_mov_dpp(d3.i, CTRL, 0xF, 0xF, true);         \
          t4_.i = __builtin_amdgcn_mov_dpp(d4.i, CTRL, 0xF, 0xF, true);         \
          S[G][0] = t0_.h; S[G][1] = t1_.h; S[G][2] = t2_.h;                    \
          S[G][3] = t3_.h; S[G][4] = t4_.h; }
        GSLOT(1, QP1)
        GSLOT(2, QP2)
        GSLOT(3, QP3)
#undef GSLOT
    };

    // ---- prologue: xp(0); raw row 1 in flight ----
    load_raw(0);
    make_xp();
    load_raw(1);

    // ---- tau = 0 (peel, keep=0) ----
    full_step(0.0f);
    make_xp();          // xp for tau=1 from raw row 1
    load_raw(2);

    // ---- tau = 1..510 ----
    for (int t = 1; t <= 510; ++t) {
        full_step(1.0f);
        make_xp();      // xp for tau=t+1
        load_raw((t + 2 <= 511) ? (t + 2) : 511);
    }
    // ---- tau = 511 ----
    full_step(1.0f);

    // ---- epilogue: h2(511) from S = (h1(511), h2(510)) ----
    float h2f[5];
    #pragma unroll
    for (int r = 0; r < 5; ++r) {
        float q0 = b1v[r], q1 = 0.f, q2 = 0.f, q3 = 0.f;
        #pragma unroll
        for (int g = 0; g < 4; ++g) {
            q0 = fdot2(S[g][0], W1[r][g*5+0], q0);
            q1 = fdot2(S[g][1], W1[r][g*5+1], q1);
            q2 = fdot2(S[g][2], W1[r][g*5+2], q2);
            q3 = fdot2(S[g][3], W1[r][g*5+3], q3);
            q0 = fdot2(S[g][4], W1[r][g*5+4], q0);
        }
        h2f[r] = tanh_pre((q0 + q1) + (q2 + q3));
    }
    CFENCE();
    #pragma unroll
    for (int r = 0; r < 5; ++r) ldsF[q][5 * c + r] = h2f[r];
    CFENCE();

    // ---- FC: lanes c<2 emit out[samp][c] ----
    if (c < DOUT) {
        float acc = fc_b[c];
        #pragma unroll
        for (int j = 0; j < H_; ++j) acc = fmaf(ldsF[q][j], fc_w[c * H_ + j], acc);
        out[samp * DOUT + c] = acc;
    }
}

extern "C" void kernel_launch(void* const* d_in, const int* in_sizes, int n_in,
                              void* d_out, int out_size, void* d_ws, size_t ws_size,
                              hipStream_t stream) {
    (void)in_sizes; (void)n_in; (void)d_ws; (void)ws_size; (void)out_size;
    const float* x     = (const float*)d_in[0];
    const float* w_ih0 = (const float*)d_in[1];
    const float* w_hh0 = (const float*)d_in[2];
    const float* b_ih0 = (const float*)d_in[3];
    const float* b_hh0 = (const float*)d_in[4];
    const float* w_ih1 = (const float*)d_in[5];
    const float* w_hh1 = (const float*)d_in[6];
    const float* b_ih1 = (const float*)d_in[7];
    const float* b_hh1 = (const float*)d_in[8];
    const float* fc_w  = (const float*)d_in[9];
    const float* fc_b  = (const float*)d_in[10];
    float* out = (float*)d_out;

    hipLaunchKernelGGL(rnn_quad, dim3(B_ / 16), dim3(64), 0, stream,
                       x, w_ih0, w_hh0, b_ih0, b_hh0,
                       w_ih1, w_hh1, b_ih1, b_hh1, fc_w, fc_b, out);
}

// Round 19
// 163.810 us; speedup vs baseline: 1.9461x; 1.9461x over previous
//
#include <hip/hip_runtime.h>
#include <cstdint>

// Problem constants (from reference)
constexpr int B_   = 4096;
constexpr int T_   = 512;
constexpr int DIN  = 10;
constexpr int H_   = 20;
constexpr int DOUT = 2;

constexpr int SPW = 3;            // samples per wave (3 x 20 = 60 active lanes)
constexpr int CH  = 2;            // timesteps per x-chunk
constexpr int XV  = CH * DIN / 4; // float4 prefetch regs per chunk
constexpr int RSW = 20;           // state row stride in dwords (80 B, 16B-aligned)

typedef float    v2f  __attribute__((ext_vector_type(2)));
typedef float    v4f  __attribute__((ext_vector_type(4)));
typedef int      v4i  __attribute__((ext_vector_type(4)));
typedef _Float16 h2t  __attribute__((ext_vector_type(2)));
typedef __fp16   fp2t __attribute__((ext_vector_type(2)));

constexpr float SCL = 2.885390082f;   // 2*log2(e), folded into weights/biases

__device__ __forceinline__ v2f pkfma(v2f a, v2f b, v2f c) {
    return __builtin_elementwise_fma(a, b, c);
}

// v_dot2_f32_f16: D = a.x*b.x + a.y*b.y + c (f32 accumulate, one instr)
__device__ __forceinline__ float fdot2(h2t a, h2t b, float c) {
#if __has_builtin(__builtin_amdgcn_fdot2)
    return __builtin_amdgcn_fdot2(a, b, c, false);
#else
    return fmaf((float)a.x, (float)b.x, fmaf((float)a.y, (float)b.y, c));
#endif
}

// tanh from PRE-SCALED input s = 2*log2e*v: 4-op chain, exact saturation
__device__ __forceinline__ float tanh_pre(float s) {
    float e = __builtin_amdgcn_exp2f(s);
    float r = __builtin_amdgcn_rcpf(e + 1.0f);
    return fmaf(-2.0f, r, 1.0f);
}

union HI  { int i; h2t h; fp2t f; };
union V4S { v4i v; h2t h[4]; };

// Skewed 2-layer RNN, INTERLEAVED f16 state exchange.
// Key invariant: the step at tau produces exactly the pair
//   (h1(tau), h2(tau-1))  -- and the next step's L1 consumes exactly that
// pair per index j:  h2(tau) = tanh(b1 + wi1[j].h1(tau) + wh1[j].h2(tau-1)).
// So pack both into ONE dword (cvt_pkrtz) -> ONE ds_write_b32 per step
// (N_DS: 7 -> 6; model: wall ~= 394 + 38*N_DS from R9-R18 fits), and the
// state dword is directly the fdot2 operand for L1 (weights (wi1,wh1))
// and for L0 (weights (wh0,0), half-wasted but off-chain).
extern "C" __global__ void __launch_bounds__(64, 1)
rnn_il(const float* __restrict__ x,
       const float* __restrict__ w_ih0, const float* __restrict__ w_hh0,
       const float* __restrict__ b_ih0, const float* __restrict__ b_hh0,
       const float* __restrict__ w_ih1, const float* __restrict__ w_hh1,
       const float* __restrict__ b_ih1, const float* __restrict__ b_hh1,
       const float* __restrict__ fc_w, const float* __restrict__ fc_b,
       float* __restrict__ out)
{
    const int lane = threadIdx.x;
    const int sl   = lane / H_;          // 0..2 active, 3 = idle lanes 60..63
    const int i    = lane - sl * H_;     // h-index 0..19
    const int samp = blockIdx.x * SPW + sl;
    const int sc   = (samp < B_) ? samp : (B_ - 1);   // clamped for safe loads
    const int slc  = (sl < SPW) ? sl : SPW;           // idle lanes -> spare row

    __shared__ __align__(16) int   hs[(SPW + 1) * RSW];   // interleaved state
    __shared__ float ldsF[SPW + 1][H_];                   // epilogue FC buffer
    int* row = &hs[slc * RSW];

    // ---- weights as f16 pairs vs the interleaved state dword, pre-scaled ----
    // state dword j = (h1[j], h2prev[j]):
    //   L0 pair (wh0[j], 0); L1 pair (wi1[j], wh1[j])
    h2t WA0[H_], WA1[H_];
    #pragma unroll
    for (int j = 0; j < H_; ++j) {
        WA0[j] = h2t{(_Float16)(SCL * w_hh0[i * H_ + j]), (_Float16)0.f};
        WA1[j] = h2t{(_Float16)(SCL * w_ih1[i * H_ + j]),
                     (_Float16)(SCL * w_hh1[i * H_ + j])};
    }
    // x-projection weights (f32 pairs, pre-scaled)
    v2f wi0p[DIN / 2];
    {
        const v2f* p = reinterpret_cast<const v2f*>(w_ih0 + i * DIN);
        #pragma unroll
        for (int k = 0; k < DIN / 2; ++k) {
            v2f v = p[k];
            wi0p[k] = (v2f){v.x * SCL, v.y * SCL};
        }
    }
    const float bias0 = (b_ih0[i] + b_hh0[i]) * SCL;
    const float bias1 = (b_ih1[i] + b_hh1[i]) * SCL;

    // ---- gathered interleaved state: S[j] = (h1(tau-1)[j], h2(tau-2)[j]) ----
    h2t S[H_];
    #pragma unroll
    for (int j = 0; j < H_; ++j) S[j] = h2t{(_Float16)0.f, (_Float16)0.f};

    const v4f* xb = reinterpret_cast<const v4f*>(x + (size_t)sc * (T_ * DIN));

    v4f xv[XV];
    #pragma unroll
    for (int k = 0; k < XV; ++k) xv[k] = xb[k];

    auto getpair = [&](int p) -> v2f {
        v4f v = xv[p >> 1];
        return (p & 1) ? (v2f){v.z, v.w} : (v2f){v.x, v.y};
    };

    auto consume_xp = [&](float (&xp)[CH]) {
        #pragma unroll
        for (int m = 0; m < CH; ++m) {
            v2f acc = (v2f){bias0, 0.f};
            #pragma unroll
            for (int q = 0; q < DIN / 2; ++q)
                acc = pkfma(getpair(m * (DIN / 2) + q), wi0p[q], acc);
            xp[m] = acc.x + acc.y;
        }
    };

    // exchange: ONE b32 write + 5 fused b128 reads (6 DS ops total)
    auto exchange = [&](float h1n, float h2n) {
        HI pk; pk.f = __builtin_amdgcn_cvt_pkrtz(h1n, h2n);
        row[i] = pk.i;
        V4S r[5];
        #pragma unroll
        for (int k = 0; k < 5; ++k)
            r[k].v = reinterpret_cast<const v4i*>(row)[k];
        #pragma unroll
        for (int k = 0; k < 5; ++k) {
            S[4*k+0] = r[k].h[0]; S[4*k+1] = r[k].h[1];
            S[4*k+2] = r[k].h[2]; S[4*k+3] = r[k].h[3];
        }
    };

    // one skewed step: h1(tau) [L0] and h2(tau-1) [L1] from committed S
    auto full_step = [&](float xpm) {
        // ---- L0: 20 dot2 (h1 half only), 4 chains ----
        float a0 = xpm, a1 = 0.f, a2 = 0.f, a3 = 0.f;
        #pragma unroll
        for (int j = 0; j < H_; j += 4) {
            a0 = fdot2(S[j+0], WA0[j+0], a0);
            a1 = fdot2(S[j+1], WA0[j+1], a1);
            a2 = fdot2(S[j+2], WA0[j+2], a2);
            a3 = fdot2(S[j+3], WA0[j+3], a3);
        }
        float h1n = tanh_pre((a0 + a1) + (a2 + a3));

        // ---- L1: 20 dot2, both halves used, 4 chains ----
        float b0 = bias1, b1 = 0.f, b2 = 0.f, b3 = 0.f;
        #pragma unroll
        for (int j = 0; j < H_; j += 4) {
            b0 = fdot2(S[j+0], WA1[j+0], b0);
            b1 = fdot2(S[j+1], WA1[j+1], b1);
            b2 = fdot2(S[j+2], WA1[j+2], b2);
            b3 = fdot2(S[j+3], WA1[j+3], b3);
        }
        float h2n = tanh_pre((b0 + b1) + (b2 + b3));

        exchange(h1n, h2n);
    };

    // ---- chunk 0, tau=0 peeled: h1(0)=tanh(xp[0]); h2 half = 0 ----
    {
        float xp[CH];
        consume_xp(xp);
        #pragma unroll
        for (int k = 0; k < XV; ++k) xv[k] = xb[(CH * DIN) / 4 + k];

        float h1n = tanh_pre(xp[0]);
        exchange(h1n, 0.0f);

        #pragma unroll
        for (int m = 1; m < CH; ++m) full_step(xp[m]);
    }

    // ---- main loop ----
    for (int t0 = CH; t0 < T_; t0 += CH) {
        float xp[CH];
        consume_xp(xp);
        {
            const int t0n = (t0 + CH < T_) ? (t0 + CH) : 0;
            #pragma unroll
            for (int k = 0; k < XV; ++k) xv[k] = xb[(t0n * DIN) / 4 + k];
        }
        #pragma unroll
        for (int m = 0; m < CH; ++m) full_step(xp[m]);
    }

    // ---- epilogue: h2(T-1) from S = (h1(T-1), h2(T-2)) ----
    {
        float b0 = bias1, b1 = 0.f, b2 = 0.f, b3 = 0.f;
        #pragma unroll
        for (int j = 0; j < H_; j += 4) {
            b0 = fdot2(S[j+0], WA1[j+0], b0);
            b1 = fdot2(S[j+1], WA1[j+1], b1);
            b2 = fdot2(S[j+2], WA1[j+2], b2);
            b3 = fdot2(S[j+3], WA1[j+3], b3);
        }
        float h2n = tanh_pre((b0 + b1) + (b2 + b3));
        ldsF[slc][i] = h2n;                 // f32 side buffer for FC
    }

    // ---- FC: lanes i<2 emit out[samp][i] ----
    if (sl < SPW && samp < B_ && i < DOUT) {
        float acc = fc_b[i];
        #pragma unroll
        for (int j = 0; j < H_; ++j) acc = fmaf(ldsF[slc][j], fc_w[i * H_ + j], acc);
        out[samp * DOUT + i] = acc;
    }
}

extern "C" void kernel_launch(void* const* d_in, const int* in_sizes, int n_in,
                              void* d_out, int out_size, void* d_ws, size_t ws_size,
                              hipStream_t stream) {
    (void)in_sizes; (void)n_in; (void)d_ws; (void)ws_size; (void)out_size;
    const float* x     = (const float*)d_in[0];
    const float* w_ih0 = (const float*)d_in[1];
    const float* w_hh0 = (const float*)d_in[2];
    const float* b_ih0 = (const float*)d_in[3];
    const float* b_hh0 = (const float*)d_in[4];
    const float* w_ih1 = (const float*)d_in[5];
    const float* w_hh1 = (const float*)d_in[6];
    const float* b_ih1 = (const float*)d_in[7];
    const float* b_hh1 = (const float*)d_in[8];
    const float* fc_w  = (const float*)d_in[9];
    const float* fc_b  = (const float*)d_in[10];
    float* out = (float*)d_out;

    const int grid = (B_ + SPW - 1) / SPW;   // 1366 single-wave blocks
    hipLaunchKernelGGL(rnn_il, dim3(grid), dim3(64), 0, stream,
                       x, w_ih0, w_hh0, b_ih0, b_hh0,
                       w_ih1, w_hh1, b_ih1, b_hh1, fc_w, fc_b, out);
}